// Round 2
// baseline (329.147 us; speedup 1.0000x reference)
//
#include <hip/hip_runtime.h>
#include <math.h>

typedef float f4 __attribute__((ext_vector_type(4)));

// x: [B=4, A=64, S=64, C=64, F=64] fp32, processed one b at a time:
//   pool(b):  x[b] -> ps[a][s][f] (sum over c), pc2[a*8+sc][c][f] (sum over 8 s)
//   ra(b):    ps,pc2 -> m_a/m_s/m_c (in LDS) -> att_a/att_s/att_c[b]
//   scale(b): out[b] = x[b] * att_c * att_s * att_a   (x[b] hot in L3)

// ---------------- pool: grid 512 = a*8+sc, block 256 (4 waves) ----------------
__global__ __launch_bounds__(256) void pool_kernel(
    const float* __restrict__ xb,    // x + b*16M floats
    float* __restrict__ ps,          // [64 a][64 s][64 f]  (1 MiB)
    float* __restrict__ pc2)         // [512 blk][64 c][64 f] (8 MiB)
{
    const int blk = blockIdx.x;
    const int a = blk >> 3, sc = blk & 7;
    const int t = threadIdx.x;
    const int w = t >> 6, lane = t & 63;
    const int fg = lane & 15;        // f = fg*4
    const int cg = lane >> 4;        // c-quarter

    const float* xa = xb + (size_t)a * 262144;

    f4 csum[16];
#pragma unroll
    for (int j = 0; j < 16; ++j) csum[j] = f4{0.f, 0.f, 0.f, 0.f};

    __shared__ float lds[4][4096];   // per-wave [c][f] partial sums (64 KiB)

#pragma unroll
    for (int r = 0; r < 2; ++r) {
        const int s = sc * 8 + w + r * 4;
        const float* xs = xa + s * 4096 + cg * 1024 + fg * 4;
        f4 ssum = f4{0.f, 0.f, 0.f, 0.f};
#pragma unroll
        for (int j = 0; j < 16; ++j) {
            f4 v = *(const f4*)(xs + j * 64);
            ssum += v;
            csum[j] += v;
        }
        // butterfly over cg lane bits (16,32): sum over all 64 c
#pragma unroll
        for (int i = 0; i < 4; ++i) ssum[i] += __shfl_xor(ssum[i], 16);
#pragma unroll
        for (int i = 0; i < 4; ++i) ssum[i] += __shfl_xor(ssum[i], 32);
        if (cg == 0)
            *(f4*)(ps + (size_t)a * 4096 + s * 64 + fg * 4) = ssum;
    }

    // per-wave csum -> LDS slice, single sync, parallel 4-way merge
#pragma unroll
    for (int j = 0; j < 16; ++j)
        *(f4*)(&lds[w][(cg * 16 + j) * 64 + fg * 4]) = csum[j];
    __syncthreads();

    float* dst = pc2 + (size_t)blk * 4096;
#pragma unroll
    for (int k = 0; k < 4; ++k) {
        const int p = k * 1024 + t * 4;      // consecutive lanes -> consecutive f4
        f4 acc = *(const f4*)(&lds[0][p]);
#pragma unroll
        for (int w2 = 1; w2 < 4; ++w2) acc += *(const f4*)(&lds[w2][p]);
        *(f4*)(dst + p) = acc;
    }
}

// ------------- ra: fused reduce + tri-axis attention. grid 64 (f), block 256 -------------
__global__ __launch_bounds__(256) void ra_kernel(
    const float* __restrict__ ps, const float* __restrict__ pc2,
    const float* __restrict__ w1_a, const float* __restrict__ w1_s, const float* __restrict__ w1_c,
    const float* __restrict__ w2_a, const float* __restrict__ w2_s, const float* __restrict__ w2_c,
    float* __restrict__ att_a, float* __restrict__ att_s, float* __restrict__ att_c) // + b*4096
{
    const int f = blockIdx.x;
    const int t = threadIdx.x;
    const int d = t >> 2, q = t & 3;

    __shared__ float pm[3][64][4];
    __shared__ float mld[3][64];
    __shared__ float w1ld[3][1024];  // [axis][d*16+e]
    __shared__ float w2ld[3][1024];  // [axis][e*64+d]
    __shared__ float zld[3][16];

    // stage weights for this filter (coalesced f4)
    {
        const float* w1p[3] = {w1_a, w1_s, w1_c};
        const float* w2p[3] = {w2_a, w2_s, w2_c};
#pragma unroll
        for (int ax = 0; ax < 3; ++ax) {
            *(f4*)(&w1ld[ax][t * 4]) = *(const f4*)(w1p[ax] + (size_t)f * 1024 + t * 4);
            *(f4*)(&w2ld[ax][t * 4]) = *(const f4*)(w2p[ax] + (size_t)f * 1024 + t * 4);
        }
    }

    // partial pooled means (4-way q split per output d)
    {
        float sa = 0.f, ss = 0.f, sc_ = 0.f;
#pragma unroll 8
        for (int i = 0; i < 16; ++i) {
            sa += ps[(size_t)d * 4096 + (q + 4 * i) * 64 + f];   // m_a[d]: sum over s
            ss += ps[(size_t)(q + 4 * i) * 4096 + d * 64 + f];   // m_s[d]: sum over a
        }
#pragma unroll 8
        for (int i = 0; i < 128; ++i)
            sc_ += pc2[(size_t)(q + 4 * i) * 4096 + d * 64 + f]; // m_c[d]: sum over 512 chunks
        pm[0][d][q] = sa; pm[1][d][q] = ss; pm[2][d][q] = sc_;
    }
    __syncthreads();
    if (t < 192) {
        const int ax = t >> 6, dd = t & 63;
        mld[ax][dd] = (pm[ax][dd][0] + pm[ax][dd][1] + pm[ax][dd][2] + pm[ax][dd][3])
                      * (1.f / 4096.f);
    }
    __syncthreads();
    if (t < 48) {
        const int ax = t >> 4, e = t & 15;
        float acc = 0.f;
#pragma unroll
        for (int dd = 0; dd < 64; ++dd) acc += mld[ax][dd] * w1ld[ax][dd * 16 + e];
        zld[ax][e] = fmaxf(acc, 0.f);
    }
    __syncthreads();
    if (t < 192) {
        const int ax = t >> 6, dd = t & 63;
        float acc = 0.f;
#pragma unroll
        for (int e = 0; e < 16; ++e) acc += zld[ax][e] * w2ld[ax][e * 64 + dd];
        const float att = 1.f / (1.f + expf(-acc));
        float* dst = ax == 0 ? att_a : (ax == 1 ? att_s : att_c);
        dst[dd * 64 + f] = att;
    }
}

// ---------------- scale: grid 512 = a*8+sc, block 256 ----------------
__global__ __launch_bounds__(256) void scale_kernel(
    const float* __restrict__ xb,
    const float* __restrict__ aab, const float* __restrict__ asb,
    const float* __restrict__ acb,
    float* __restrict__ ob)
{
    const int blk = blockIdx.x;
    const int sc = blk & 7;
    const int a = blk >> 3;
    const int t = threadIdx.x;
    const int fg = t & 15;
    const int cq = t >> 4;

    __shared__ float acl[64][68];   // +4 pad: conflict-free column reads
    __shared__ float asl[8][64];

    {
        const f4* srcc = (const f4*)acb;
#pragma unroll
        for (int i = 0; i < 4; ++i) {
            int qq = t + 256 * i;                 // f4 id: c = qq>>4, f = (qq&15)*4
            f4 v = srcc[qq];
            *(f4*)(&acl[qq >> 4][(qq & 15) * 4]) = v;
        }
        if (t < 128) {
            f4 v = *(const f4*)(asb + sc * 512 + t * 4);
            *(f4*)(&asl[t >> 4][(t & 15) * 4]) = v;
        }
    }
    f4 aa = *(const f4*)(aab + a * 64 + fg * 4);
    __syncthreads();

    const size_t base = (size_t)(a * 64 + sc * 8) * 4096;
    const float* xs = xb + base;
    float* os = ob + base;

    for (int sl = 0; sl < 8; ++sl) {
        f4 m0 = aa * *(const f4*)(&asl[sl][fg * 4]);
#pragma unroll
        for (int k = 0; k < 4; ++k) {
            const int c = k * 16 + cq;
            const size_t off = (size_t)(sl * 64 + c) * 64 + fg * 4;
            f4 v = *(const f4*)(xs + off);
            f4 acv = *(const f4*)(&acl[c][fg * 4]);
            *(f4*)(os + off) = v * m0 * acv;
        }
    }
}

extern "C" void kernel_launch(void* const* d_in, const int* in_sizes, int n_in,
                              void* d_out, int out_size, void* d_ws, size_t ws_size,
                              hipStream_t stream)
{
    (void)in_sizes; (void)n_in; (void)out_size; (void)ws_size;
    const float* x    = (const float*)d_in[0];
    const float* w1_a = (const float*)d_in[1];
    const float* w1_s = (const float*)d_in[2];
    const float* w1_c = (const float*)d_in[3];
    const float* w2_a = (const float*)d_in[4];
    const float* w2_s = (const float*)d_in[5];
    const float* w2_c = (const float*)d_in[6];
    float* out = (float*)d_out;

    // att tables in ws (tiny, proven-safe size)
    float* att_a = (float*)d_ws;          // [4][4096]
    float* att_s = att_a + 16384;
    float* att_c = att_s + 16384;

    for (int b = 0; b < 4; ++b) {
        const float* xb = x   + (size_t)b * 16777216;
        float*       ob = out + (size_t)b * 16777216;
        // partials live in out[b]'s region; fully consumed by ra(b) before
        // scale(b) rewrites every element of out[b] (stream-ordered).
        float* ps  = ob;                   // 262144 floats (1 MiB)
        float* pc2 = ob + 262144;          // 2097152 floats (8 MiB)
        float* aab = att_a + b * 4096;
        float* asb = att_s + b * 4096;
        float* acb = att_c + b * 4096;

        hipLaunchKernelGGL(pool_kernel,  dim3(512), dim3(256), 0, stream, xb, ps, pc2);
        hipLaunchKernelGGL(ra_kernel,    dim3(64),  dim3(256), 0, stream,
                           ps, pc2, w1_a, w1_s, w1_c, w2_a, w2_s, w2_c,
                           aab, asb, acb);
        hipLaunchKernelGGL(scale_kernel, dim3(512), dim3(256), 0, stream,
                           xb, aab, asb, acb, ob);
    }
}

// Round 3
// 173.863 us; speedup vs baseline: 1.8931x; 1.8931x over previous
//
#include <hip/hip_runtime.h>
#include <math.h>

typedef float f4 __attribute__((ext_vector_type(4)));

// x: [B=4][A=64][S=64][C=64][F=64] fp32. Processed in 2 batch-PAIRS so the
// pair's x (128 MiB) stays resident in the 256 MiB Infinity Cache between the
// pooling read and the scale re-read. out is written with non-temporal stores
// so it doesn't evict x from L3.

static __device__ __forceinline__ f4 ldnt(const float* p) {
    return __builtin_nontemporal_load((const f4*)p);
}
static __device__ __forceinline__ void stnt(float* p, f4 v) {
    __builtin_nontemporal_store(v, (f4*)p);
}

// ---------------- pool: grid 1024 = (bb,a,h), block 256 (4 waves) ----------------
// Each block: 8 s-rows of slab (bb,a). Wave w covers s = h*8 + w*2 + {0,1}.
// Outputs: ps[bb][a][s][f] (2 MiB/pair), pc2[chunk][c][f] (2048 chunks, 32 MiB/pair),
// chunk = blk*2 + {0,1} after pairwise wave merge.
__global__ __launch_bounds__(256) void pool_kernel(
    const float* __restrict__ xp,    // x + pair*32M floats
    float* __restrict__ ps,
    float* __restrict__ pc2)
{
    const int blk = blockIdx.x;
    const int bb = blk >> 9;
    const int a  = (blk >> 3) & 63;
    const int h  = blk & 7;
    const int t  = threadIdx.x;
    const int w  = t >> 6, lane = t & 63;
    const int fg = lane & 15;        // f = fg*4
    const int cg = lane >> 4;        // c-quarter

    const float* xa = xp + (size_t)(bb * 64 + a) * 262144;

    f4 csum[16];
#pragma unroll
    for (int j = 0; j < 16; ++j) csum[j] = f4{0.f, 0.f, 0.f, 0.f};

#pragma unroll
    for (int r = 0; r < 2; ++r) {
        const int s = h * 8 + w * 2 + r;
        const float* xs = xa + s * 4096 + cg * 1024 + fg * 4;
        f4 ssum = f4{0.f, 0.f, 0.f, 0.f};
#pragma unroll
        for (int j = 0; j < 16; ++j) {
            f4 v = *(const f4*)(xs + j * 64);
            ssum += v;
            csum[j] += v;
        }
        // butterfly over cg lane bits: sum over all 64 c
#pragma unroll
        for (int i = 0; i < 4; ++i) ssum[i] += __shfl_xor(ssum[i], 16);
#pragma unroll
        for (int i = 0; i < 4; ++i) ssum[i] += __shfl_xor(ssum[i], 32);
        if (cg == 0)
            *(f4*)(ps + ((size_t)(bb * 64 + a) * 64 + s) * 64 + fg * 4) = ssum;
    }

    // pairwise wave merge: waves 2,3 dump; waves 0,1 add and write chunk.
    __shared__ float lds[2][4096];   // 32 KiB
    if (w >= 2) {
#pragma unroll
        for (int j = 0; j < 16; ++j)
            *(f4*)(&lds[w - 2][(cg * 16 + j) * 64 + fg * 4]) = csum[j];
    }
    __syncthreads();
    if (w < 2) {
        float* dst = pc2 + (size_t)(blk * 2 + w) * 4096;
#pragma unroll
        for (int j = 0; j < 16; ++j) {
            f4 o = *(const f4*)(&lds[w][(cg * 16 + j) * 64 + fg * 4]);
            *(f4*)(dst + (cg * 16 + j) * 64 + fg * 4) = csum[j] + o;
        }
    }
}

// ---------------- reduce: grid 384, block 256. Wave-coalesced (256 B rows) ----------------
// blocks 0..127: m_c (heavy, launched first), 128..255: m_s, 256..383: m_a.
__global__ __launch_bounds__(256) void reduce_kernel(
    const float* __restrict__ ps, const float* __restrict__ pc2,
    float* __restrict__ m_s, float* __restrict__ m_a, float* __restrict__ m_c)
{
    const int blk = blockIdx.x;
    const int k2 = blk >> 7;                 // 0: m_c, 1: m_s, 2: m_a
    const int bb = (blk >> 6) & 1;
    const int d  = blk & 63;
    const int t  = threadIdx.x;
    const int g  = t >> 6, f = t & 63;

    float acc = 0.f;
    if (k2 == 0) {
#pragma unroll 8
        for (int i = g; i < 1024; i += 4)
            acc += pc2[(size_t)(bb * 1024 + i) * 4096 + d * 64 + f];
    } else if (k2 == 1) {
#pragma unroll 8
        for (int i = g; i < 64; i += 4)
            acc += ps[((size_t)(bb * 64 + i) * 64 + d) * 64 + f];
    } else {
#pragma unroll 8
        for (int i = g; i < 64; i += 4)
            acc += ps[((size_t)(bb * 64 + d) * 64 + i) * 64 + f];
    }

    __shared__ float sm[4][64];
    sm[g][f] = acc;
    __syncthreads();
    if (t < 64) {
        float tot = (sm[0][t] + sm[1][t] + sm[2][t] + sm[3][t]) * (1.f / 4096.f);
        float* dst = k2 == 0 ? m_c : (k2 == 1 ? m_s : m_a);
        dst[((size_t)bb * 64 + d) * 64 + t] = tot;
    }
}

// ---------------- attn: grid 192 = (axis,f), block 64 ----------------
__global__ __launch_bounds__(64) void attn_kernel(
    const float* __restrict__ m_s, const float* __restrict__ m_a, const float* __restrict__ m_c,
    const float* __restrict__ w1_a, const float* __restrict__ w1_s, const float* __restrict__ w1_c,
    const float* __restrict__ w2_a, const float* __restrict__ w2_s, const float* __restrict__ w2_c,
    float* __restrict__ att_a_p, float* __restrict__ att_s_p, float* __restrict__ att_c_p)
{
    const int axis = blockIdx.x >> 6;
    const int f    = blockIdx.x & 63;
    const float* m  = axis == 0 ? m_a  : (axis == 1 ? m_s  : m_c);
    const float* w1 = axis == 0 ? w1_a : (axis == 1 ? w1_s : w1_c);  // [F,64,16]
    const float* w2 = axis == 0 ? w2_a : (axis == 1 ? w2_s : w2_c);  // [F,16,64]
    float* attp     = axis == 0 ? att_a_p : (axis == 1 ? att_s_p : att_c_p);

    __shared__ float w1ld[1024];
    __shared__ float w2ld[1024];
    __shared__ float mld[2][64];
    __shared__ float zld[2][16];
    const int t = threadIdx.x;

    {
        const f4* s1 = (const f4*)(w1 + (size_t)f * 1024);
        const f4* s2 = (const f4*)(w2 + (size_t)f * 1024);
#pragma unroll
        for (int i = 0; i < 4; ++i) {
            ((f4*)w1ld)[t + 64 * i] = s1[t + 64 * i];
            ((f4*)w2ld)[t + 64 * i] = s2[t + 64 * i];
        }
#pragma unroll
        for (int bb = 0; bb < 2; ++bb)
            mld[bb][t] = m[((size_t)bb * 64 + t) * 64 + f];
    }
    __syncthreads();
    if (t < 32) {
        const int bb = t >> 4, e = t & 15;
        float acc = 0.f;
#pragma unroll
        for (int dd = 0; dd < 64; ++dd) acc += mld[bb][dd] * w1ld[dd * 16 + e];
        zld[bb][e] = fmaxf(acc, 0.f);
    }
    __syncthreads();
#pragma unroll
    for (int bb = 0; bb < 2; ++bb) {
        float acc = 0.f;
#pragma unroll
        for (int e = 0; e < 16; ++e) acc += zld[bb][e] * w2ld[e * 64 + t];
        attp[((size_t)bb * 64 + t) * 64 + f] = 1.f / (1.f + expf(-acc));
    }
}

// ---------------- scale: grid 1024 = (bb,a,so), block 256 ----------------
__global__ __launch_bounds__(256) void scale_kernel(
    const float* __restrict__ xp,
    const float* __restrict__ aab, const float* __restrict__ asb,
    const float* __restrict__ acb,
    float* __restrict__ op)
{
    const int blk = blockIdx.x;
    const int bb = blk >> 9;
    const int a  = (blk >> 3) & 63;
    const int so = blk & 7;
    const int t  = threadIdx.x;
    const int fg = t & 15;
    const int cq = t >> 4;

    __shared__ float acl[64][68];   // +4 pad: conflict-free column reads
    __shared__ float asl[8][64];

    {
        const f4* srcc = (const f4*)(acb + (size_t)bb * 4096);
#pragma unroll
        for (int i = 0; i < 4; ++i) {
            int qq = t + 256 * i;                 // f4 id: c = qq>>4, f = (qq&15)*4
            f4 v = srcc[qq];
            *(f4*)(&acl[qq >> 4][(qq & 15) * 4]) = v;
        }
        if (t < 128) {
            f4 v = *(const f4*)(asb + (size_t)bb * 4096 + so * 512 + t * 4);
            *(f4*)(&asl[t >> 4][(t & 15) * 4]) = v;
        }
    }
    f4 aa = *(const f4*)(aab + (size_t)bb * 4096 + a * 64 + fg * 4);
    __syncthreads();

    const size_t base = (size_t)bb * 16777216 + (size_t)(a * 64 + so * 8) * 4096;
    const float* xs = xp + base;
    float* os = op + base;

    for (int sl = 0; sl < 8; ++sl) {
        f4 m0 = aa * *(const f4*)(&asl[sl][fg * 4]);
#pragma unroll
        for (int k = 0; k < 4; ++k) {
            const int c = k * 16 + cq;
            const size_t off = (size_t)(sl * 64 + c) * 64 + fg * 4;
            f4 v = ldnt(xs + off);
            f4 acv = *(const f4*)(&acl[c][fg * 4]);
            stnt(os + off, v * m0 * acv);
        }
    }
}

extern "C" void kernel_launch(void* const* d_in, const int* in_sizes, int n_in,
                              void* d_out, int out_size, void* d_ws, size_t ws_size,
                              hipStream_t stream)
{
    (void)in_sizes; (void)n_in; (void)out_size; (void)ws_size;
    const float* x    = (const float*)d_in[0];
    const float* w1_a = (const float*)d_in[1];
    const float* w1_s = (const float*)d_in[2];
    const float* w1_c = (const float*)d_in[3];
    const float* w2_a = (const float*)d_in[4];
    const float* w2_s = (const float*)d_in[5];
    const float* w2_c = (const float*)d_in[6];
    float* out = (float*)d_out;

    // Small tables in ws (288 KiB total).
    float* m_s   = (float*)d_ws;          // [2][64][64]
    float* m_a   = m_s + 8192;
    float* m_c   = m_a + 8192;
    float* att_a = m_c + 8192;            // [4][64][64] (global b index)
    float* att_s = att_a + 16384;
    float* att_c = att_s + 16384;

    for (int pair = 0; pair < 2; ++pair) {
        const float* xp = x   + (size_t)pair * 33554432;
        float*       op = out + (size_t)pair * 33554432;
        // Big partials live in out's pair region; fully consumed by reduce
        // before scale rewrites every element of the region (stream-ordered).
        float* ps  = op;                   // 524288 floats (2 MiB)
        float* pc2 = op + 524288;          // 8388608 floats (32 MiB)
        float* aab = att_a + (size_t)pair * 8192;
        float* asb = att_s + (size_t)pair * 8192;
        float* acb = att_c + (size_t)pair * 8192;

        hipLaunchKernelGGL(pool_kernel,   dim3(1024), dim3(256), 0, stream, xp, ps, pc2);
        hipLaunchKernelGGL(reduce_kernel, dim3(384),  dim3(256), 0, stream,
                           ps, pc2, m_s, m_a, m_c);
        hipLaunchKernelGGL(attn_kernel,   dim3(192),  dim3(64),  0, stream,
                           m_s, m_a, m_c, w1_a, w1_s, w1_c, w2_a, w2_s, w2_c,
                           aab, asb, acb);
        hipLaunchKernelGGL(scale_kernel,  dim3(1024), dim3(256), 0, stream,
                           xp, aab, asb, acb, op);
    }
}